// Round 4
// baseline (327.298 us; speedup 1.0000x reference)
//
#include <hip/hip_runtime.h>

// irreps: 256x0e + 128x1e + 64x2e ; x row = 960 fp32
// Persistent merged kernel, 2-stage software pipeline across 32-row tiles:
// raw fp32 x-loads for tile t+1 issued during tile t's compute (half A during
// GEMM1, half B during GEMM2), converted+staged to LDS at the next iteration.
// Swapped-operand MFMA: A = weights (m = channel), B = x/H (n = row);
// C/D col(lane&15)=row, reg-quad=4 consecutive channels -> packed b64 H-writes
// and float4 output stores.

typedef __bf16 v8bf  __attribute__((ext_vector_type(8)));
typedef __bf16 v4bf  __attribute__((ext_vector_type(4)));
typedef __bf16 v2bf  __attribute__((ext_vector_type(2)));
typedef float  v4f   __attribute__((ext_vector_type(4)));

// Phi(n) = 0.5*(1+erf(n/sqrt(2))) = gelu(n)/n, n>=0.
// Abramowitz-Stegun 7.1.26, |err(erf)| <= 1.5e-7, branch-free.
__device__ __forceinline__ float phi_from_sq(float s) {
    float n = __builtin_amdgcn_sqrtf(s);
    float z = n * 0.70710678118654752f;
    float t = __builtin_amdgcn_rcpf(fmaf(0.3275911f, z, 1.0f));
    float p = t * fmaf(t, fmaf(t, fmaf(t, fmaf(t, 1.061405429f, -1.453152027f),
                                       1.421413741f), -0.284496736f), 0.254829592f);
    float e = __builtin_amdgcn_exp2f(z * z * -1.4426950408889634f);
    return fmaf(p * e, -0.5f, 1.0f);
}

// --- pre-pass: W[u][w] fp32 -> WT[w][u] bf16, scaled by 1/sqrt(mul_in) -------
__global__ __launch_bounds__(256) void wt_prep(
    const float* __restrict__ w0, const float* __restrict__ w1,
    const float* __restrict__ w2, const float* __restrict__ w3,
    const float* __restrict__ w4, const float* __restrict__ w5,
    unsigned short* __restrict__ out)
{
    int t = blockIdx.x * 256 + threadIdx.x;
    if (t >= 172032) return;
    int s = (t < 65536) ? 0 : (t < 81920) ? 1 : (t < 86016) ? 2
          : (t < 151552) ? 3 : (t < 167936) ? 4 : 5;
    int base = (s == 0) ? 0 : (s == 1) ? 65536 : (s == 2) ? 81920
             : (s == 3) ? 86016 : (s == 4) ? 151552 : 167936;
    int lg   = (s == 0 || s == 3) ? 8 : (s == 1 || s == 4) ? 7 : 6;
    float scl = (s == 0 || s == 3) ? 0.0625f
              : (s == 1 || s == 4) ? 0.08838834764831845f : 0.125f;
    const float* p = (s == 0) ? w0 : (s == 1) ? w1 : (s == 2) ? w2
                   : (s == 3) ? w3 : (s == 4) ? w4 : w5;
    int loc = t - base;
    int w = loc >> lg;
    int u = loc & ((1 << lg) - 1);
    float v = p[(u << lg) + w] * scl;
    __bf16 h = (__bf16)v;
    out[t] = __builtin_bit_cast(unsigned short, h);
}

// --- persistent per-irrep worker --------------------------------------------
// LDS: bf16 planes [i][n(32)][u(U)], XOR-swizzled idx ^= (R&7)<<3, R=i*32+n.
template<int U, int D, int OFF>
__device__ __forceinline__ void irrep_persist(
    const float* __restrict__ x,
    const unsigned short* __restrict__ wt0,
    const unsigned short* __restrict__ wt1,
    float* __restrict__ out,
    unsigned short* lds,
    int bid, int NB)
{
    constexpr int NTILES = 2048;
    constexpr int MPW = U / 64;      // 16-wide channel tiles per wave (4 waves)
    constexpr int KT  = U / 32;      // k-steps
    constexpr int NT  = 2;           // two 16-row n-tiles
    constexpr int HIT = (D == 1) ? (16 * (U / 8)) / 256
                                 : (16 * (U / 2)) / 256;  // iters per half-tile

    const int tid  = threadIdx.x;
    const int lane = tid & 63;
    const int wid  = tid >> 6;
    const int lcol = lane & 15;
    const int loct = lane >> 4;

    // raw prefetch registers (fp32), one half-tile each
    float4 rA1[D == 1 ? HIT * 2 : 1], rB1[D == 1 ? HIT * 2 : 1];
    float2 rA2[D  > 1 ? HIT * D : 1], rB2[D  > 1 ? HIT * D : 1];

    auto issue_half = [&](int tile, int h, float4* r1, float2* r2) {
        const int row0 = tile * 32 + h * 16;
        if constexpr (D == 1) {
            #pragma unroll
            for (int o = 0; o < HIT; ++o) {
                int oct = o * 256 + tid;
                int row = oct / (U / 8);
                int u0  = (oct % (U / 8)) * 8;
                const float4* p = reinterpret_cast<const float4*>(
                    x + (long)(row0 + row) * 960 + OFF + u0);
                r1[o * 2]     = p[0];
                r1[o * 2 + 1] = p[1];
            }
        } else {
            constexpr int PAIRS = U / 2;
            #pragma unroll
            for (int g = 0; g < HIT; ++g) {
                int gid = g * 256 + tid;
                int row = gid / PAIRS;
                int u0  = (gid % PAIRS) * 2;
                const float2* p = reinterpret_cast<const float2*>(
                    x + (long)(row0 + row) * 960 + OFF + u0 * D);
                #pragma unroll
                for (int j = 0; j < D; ++j) r2[g * D + j] = p[j];
            }
        }
    };

    auto write_half = [&](int h, const float4* r1, const float2* r2) {
        if constexpr (D == 1) {
            #pragma unroll
            for (int o = 0; o < HIT; ++o) {
                int oct = o * 256 + tid;
                int row = h * 16 + oct / (U / 8);
                int u0  = (oct % (U / 8)) * 8;
                float4 fa = r1[o * 2], fb = r1[o * 2 + 1];
                v8bf hv = { (__bf16)fa.x, (__bf16)fa.y, (__bf16)fa.z, (__bf16)fa.w,
                            (__bf16)fb.x, (__bf16)fb.y, (__bf16)fb.z, (__bf16)fb.w };
                int idx = (row * U + u0) ^ ((row & 7) << 3);
                *reinterpret_cast<v8bf*>(&lds[idx]) = hv;
            }
        } else {
            constexpr int PAIRS = U / 2;
            #pragma unroll
            for (int g = 0; g < HIT; ++g) {
                int gid = g * 256 + tid;
                int row = h * 16 + gid / PAIRS;
                int u0  = (gid % PAIRS) * 2;
                float f[2 * D];
                #pragma unroll
                for (int j = 0; j < D; ++j) {
                    float2 q = r2[g * D + j];
                    f[2 * j] = q.x; f[2 * j + 1] = q.y;
                }
                #pragma unroll
                for (int i = 0; i < D; ++i) {
                    int R = i * 32 + row;
                    int idx = (R * U + u0) ^ ((R & 7) << 3);
                    v2bf h2 = { (__bf16)f[i], (__bf16)f[D + i] };
                    *reinterpret_cast<v2bf*>(&lds[idx]) = h2;
                }
            }
        }
    };

    v4f acc[D][MPW][NT];

    auto run_layer = [&](const unsigned short* __restrict__ wt) {
        #pragma unroll
        for (int i = 0; i < D; ++i)
            #pragma unroll
            for (int mt = 0; mt < MPW; ++mt)
                #pragma unroll
                for (int nt = 0; nt < NT; ++nt) {
                    v4f z = {0.f, 0.f, 0.f, 0.f};
                    acc[i][mt][nt] = z;
                }
        #pragma unroll
        for (int kt = 0; kt < KT; ++kt) {
            v8bf a[MPW];
            #pragma unroll
            for (int mt = 0; mt < MPW; ++mt) {
                int w = (wid * MPW + mt) * 16 + lcol;
                a[mt] = *reinterpret_cast<const v8bf*>(wt + w * U + kt * 32 + loct * 8);
            }
            #pragma unroll
            for (int i = 0; i < D; ++i) {
                v8bf b[NT];
                #pragma unroll
                for (int nt = 0; nt < NT; ++nt) {
                    int R = i * 32 + nt * 16 + lcol;
                    int idx = (R * U + kt * 32 + loct * 8) ^ ((R & 7) << 3);
                    b[nt] = *reinterpret_cast<const v8bf*>(&lds[idx]);
                }
                #pragma unroll
                for (int mt = 0; mt < MPW; ++mt)
                    #pragma unroll
                    for (int nt = 0; nt < NT; ++nt)
                        acc[i][mt][nt] = __builtin_amdgcn_mfma_f32_16x16x32_bf16(
                            a[mt], b[nt], acc[i][mt][nt], 0, 0, 0);
            }
        }
    };

    // ---- prologue: prefetch first tile ----
    int t = bid;
    issue_half(t, 0, rA1, rA2);
    issue_half(t, 1, rB1, rB2);

    while (t < NTILES) {
        int tn = t + NB;
        int pf = (tn < NTILES) ? tn : t;   // clamped (redundant loads on last iter)

        // stage tile t from raw regs -> LDS (loads issued long ago)
        write_half(0, rA1, rA2);
        write_half(1, rB1, rB2);
        __syncthreads();                   // x ready

        issue_half(pf, 0, rA1, rA2);       // in flight during GEMM1 + normact
        run_layer(wt0);
        __syncthreads();                   // x reads done

        // normact + packed H write (lane: n = lcol, 4 consecutive channels)
        #pragma unroll
        for (int mt = 0; mt < MPW; ++mt)
            #pragma unroll
            for (int nt = 0; nt < NT; ++nt) {
                float h[D][4];
                #pragma unroll
                for (int r = 0; r < 4; ++r) {
                    float s = 0.f;
                    #pragma unroll
                    for (int i = 0; i < D; ++i) {
                        float v = acc[i][mt][nt][r];
                        s += v * v;
                    }
                    float fac = phi_from_sq(s);
                    #pragma unroll
                    for (int i = 0; i < D; ++i) h[i][r] = acc[i][mt][nt][r] * fac;
                }
                int u0 = (wid * MPW + mt) * 16 + loct * 4;
                #pragma unroll
                for (int i = 0; i < D; ++i) {
                    int R = i * 32 + nt * 16 + lcol;
                    int idx = (R * U + u0) ^ ((R & 7) << 3);
                    v4bf hb = { (__bf16)h[i][0], (__bf16)h[i][1],
                                (__bf16)h[i][2], (__bf16)h[i][3] };
                    *reinterpret_cast<v4bf*>(&lds[idx]) = hb;
                }
            }
        __syncthreads();                   // H ready

        issue_half(pf, 1, rB1, rB2);       // in flight during GEMM2 + stores
        run_layer(wt1);

        // stores: lane writes 4*D consecutive floats at out[n][OFF + w0*D]
        {
            int row0 = t * 32;
            #pragma unroll
            for (int mt = 0; mt < MPW; ++mt)
                #pragma unroll
                for (int nt = 0; nt < NT; ++nt) {
                    int n  = row0 + nt * 16 + lcol;
                    int w0 = (wid * MPW + mt) * 16 + loct * 4;
                    float* po = out + (long)n * 960 + OFF + w0 * D;
                    float buf[4 * D];
                    #pragma unroll
                    for (int r = 0; r < 4; ++r)
                        #pragma unroll
                        for (int i = 0; i < D; ++i)
                            buf[r * D + i] = acc[i][mt][nt][r];
                    #pragma unroll
                    for (int j = 0; j < D; ++j) {
                        float4 q = { buf[4*j], buf[4*j+1], buf[4*j+2], buf[4*j+3] };
                        *reinterpret_cast<float4*>(po + 4 * j) = q;
                    }
                }
        }
        t = tn;
        __syncthreads();                   // H reads done -> LDS reusable
    }
}

// --- merged persistent kernel: block ranges per irrep, ~work-balanced --------
__global__ __launch_bounds__(256, 4) void fused_all(
    const float* __restrict__ x,
    const unsigned short* __restrict__ ws,
    float* __restrict__ out)
{
    __shared__ unsigned short lds[96 * 128];   // 24 KB, max over the 3 types
    int bid = blockIdx.x;
    if (bid < 416)
        irrep_persist<256, 1,   0>(x, ws + 0,     ws + 86016,  out, lds, bid,       416);
    else if (bid < 784)
        irrep_persist<128, 3, 256>(x, ws + 65536, ws + 151552, out, lds, bid - 416, 368);
    else
        irrep_persist< 64, 5, 640>(x, ws + 81920, ws + 167936, out, lds, bid - 784, 240);
}

extern "C" void kernel_launch(void* const* d_in, const int* in_sizes, int n_in,
                              void* d_out, int out_size, void* d_ws, size_t ws_size,
                              hipStream_t stream)
{
    const float* x  = (const float*)d_in[0];
    const float* W0 = (const float*)d_in[1];  // 256x256
    const float* W1 = (const float*)d_in[2];  // 128x128
    const float* W2 = (const float*)d_in[3];  // 64x64
    const float* W3 = (const float*)d_in[4];  // 256x256
    const float* W4 = (const float*)d_in[5];  // 128x128
    const float* W5 = (const float*)d_in[6];  // 64x64
    unsigned short* ws = (unsigned short*)d_ws;   // 344064 B of bf16 WT
    float* out = (float*)d_out;

    wt_prep<<<672, 256, 0, stream>>>(W0, W1, W2, W3, W4, W5, ws);
    fused_all<<<1024, 256, 0, stream>>>(x, ws, out);
}

// Round 5
// 141.820 us; speedup vs baseline: 2.3078x; 2.3078x over previous
//
#include <hip/hip_runtime.h>

// irreps: 256x0e + 128x1e + 64x2e ; x row = 960 fp32
// Merged kernel (R2 structure): per-irrep fused linear->normact->linear,
// bf16 MFMA, A = x/H rows from LDS, B = weight fragments from L2.
// R5: l=0 uses 64-row tiles (2x MFMA per weight load); contiguous bid->type
// ranges (I$ + per-XCD weight L2 locality).

typedef __bf16 v8bf  __attribute__((ext_vector_type(8)));
typedef float  v4f   __attribute__((ext_vector_type(4)));
typedef unsigned short u16x8 __attribute__((ext_vector_type(8)));

__device__ __forceinline__ unsigned short f2bf(float x) {
    union { float f; unsigned u; } v; v.f = x;
    unsigned r = v.u + 0x7FFFu + ((v.u >> 16) & 1u);   // RNE (finite inputs)
    return (unsigned short)(r >> 16);
}
__device__ __forceinline__ unsigned pk2(float a, float b) {
    return (unsigned)f2bf(a) | ((unsigned)f2bf(b) << 16);
}

// Phi(n) = 0.5*(1+erf(n/sqrt(2))) = gelu(n)/n, n>=0.  A&S 7.1.26.
__device__ __forceinline__ float phi_from_sq(float s) {
    float n = __builtin_amdgcn_sqrtf(s);
    float z = n * 0.70710678118654752f;
    float t = __builtin_amdgcn_rcpf(fmaf(0.3275911f, z, 1.0f));
    float p = t * fmaf(t, fmaf(t, fmaf(t, fmaf(t, 1.061405429f, -1.453152027f),
                                       1.421413741f), -0.284496736f), 0.254829592f);
    float e = __builtin_amdgcn_exp2f(z * z * -1.4426950408889634f);
    return fmaf(p * e, -0.5f, 1.0f);
}

// --- pre-pass: W[u][w] fp32 -> WT[w][u] bf16, scaled by 1/sqrt(mul_in) -------
__global__ __launch_bounds__(256) void wt_prep(
    const float* __restrict__ w0, const float* __restrict__ w1,
    const float* __restrict__ w2, const float* __restrict__ w3,
    const float* __restrict__ w4, const float* __restrict__ w5,
    unsigned short* __restrict__ out)
{
    int t = blockIdx.x * 256 + threadIdx.x;
    if (t >= 172032) return;
    int s = (t < 65536) ? 0 : (t < 81920) ? 1 : (t < 86016) ? 2
          : (t < 151552) ? 3 : (t < 167936) ? 4 : 5;
    int base = (s == 0) ? 0 : (s == 1) ? 65536 : (s == 2) ? 81920
             : (s == 3) ? 86016 : (s == 4) ? 151552 : 167936;
    int lg   = (s == 0 || s == 3) ? 8 : (s == 1 || s == 4) ? 7 : 6;
    float scl = (s == 0 || s == 3) ? 0.0625f
              : (s == 1 || s == 4) ? 0.08838834764831845f : 0.125f;
    const float* p = (s == 0) ? w0 : (s == 1) ? w1 : (s == 2) ? w2
                   : (s == 3) ? w3 : (s == 4) ? w4 : w5;
    int loc = t - base;
    int w = loc >> lg;
    int u = loc & ((1 << lg) - 1);
    out[t] = f2bf(p[(u << lg) + w] * scl);
}

// --- per-irrep worker (ROWS-row tile) ---------------------------------------
// LDS: bf16 planes [i][n(ROWS)][u(U)], XOR-swizzled idx ^= (R&7)<<3, R=i*ROWS+n.
template<int U, int D, int OFF, int ROWS>
__device__ __forceinline__ void irrep_block(
    const float* __restrict__ x,
    const unsigned short* __restrict__ wt0,
    const unsigned short* __restrict__ wt1,
    float* __restrict__ out,
    unsigned short* __restrict__ lds,
    int tile)
{
    constexpr int M    = ROWS * D;    // LDS rows
    constexpr int MT   = M / 16;      // m-tiles
    constexpr int NPW  = U / 64;      // n-tiles per wave (4 waves split n)
    constexpr int KT   = U / 32;      // k-steps
    constexpr int NR16 = ROWS / 16;   // 16-row groups per i-plane

    const int tid  = threadIdx.x;
    const int lane = tid & 63;
    const int wid  = tid >> 6;
    const int row0 = tile * ROWS;

    // ---- stage x -> LDS bf16, de-interleaved [i*ROWS+n][u] ----
    if constexpr (D == 1) {
        #pragma unroll
        for (int o = 0; o < (ROWS * (U / 8)) / 256; ++o) {
            int oct = o * 256 + tid;
            int row = oct / (U / 8);
            int u0  = (oct % (U / 8)) * 8;
            const float4* p =
                reinterpret_cast<const float4*>(x + (long)(row0 + row) * 960 + OFF + u0);
            float4 fa = p[0], fb = p[1];
            u16x8 hv = { f2bf(fa.x), f2bf(fa.y), f2bf(fa.z), f2bf(fa.w),
                         f2bf(fb.x), f2bf(fb.y), f2bf(fb.z), f2bf(fb.w) };
            int idx = (row * U + u0) ^ ((row & 7) << 3);
            *reinterpret_cast<u16x8*>(&lds[idx]) = hv;
        }
    } else {
        constexpr int PAIRS = U / 2;
        #pragma unroll
        for (int g = 0; g < (ROWS * PAIRS) / 256; ++g) {
            int gid = g * 256 + tid;
            int row = gid / PAIRS;
            int u0  = (gid % PAIRS) * 2;
            const float2* p = reinterpret_cast<const float2*>(
                x + (long)(row0 + row) * 960 + OFF + u0 * D);
            float f[2 * D];
            #pragma unroll
            for (int j = 0; j < D; ++j) { float2 q = p[j]; f[2*j] = q.x; f[2*j+1] = q.y; }
            #pragma unroll
            for (int i = 0; i < D; ++i) {
                int R = i * ROWS + row;
                int idx = (R * U + u0) ^ ((R & 7) << 3);
                *reinterpret_cast<unsigned*>(&lds[idx]) = pk2(f[i], f[D + i]);
            }
        }
    }
    __syncthreads();

    v4f acc[MT][NPW];
    const int kcol = (lane >> 4) << 3;
    const int wcol = lane & 15;
    const int g4   = (lane >> 4) << 2;

    auto run_layer = [&](const unsigned short* __restrict__ wt) {
        #pragma unroll
        for (int mt = 0; mt < MT; ++mt)
            #pragma unroll
            for (int nt = 0; nt < NPW; ++nt) {
                v4f z = {0.f, 0.f, 0.f, 0.f};
                acc[mt][nt] = z;
            }
        #pragma unroll
        for (int kt = 0; kt < KT; ++kt) {
            v8bf b[NPW];
            #pragma unroll
            for (int nt = 0; nt < NPW; ++nt) {
                int w = (wid * NPW + nt) * 16 + wcol;
                b[nt] = *reinterpret_cast<const v8bf*>(wt + w * U + kt * 32 + kcol);
            }
            #pragma unroll
            for (int mt = 0; mt < MT; ++mt) {
                int R = mt * 16 + wcol;
                int idx = (R * U + kt * 32 + kcol) ^ ((R & 7) << 3);
                v8bf a = *reinterpret_cast<const v8bf*>(&lds[idx]);
                #pragma unroll
                for (int nt = 0; nt < NPW; ++nt)
                    acc[mt][nt] = __builtin_amdgcn_mfma_f32_16x16x32_bf16(
                        a, b[nt], acc[mt][nt], 0, 0, 0);
            }
        }
    };

    run_layer(wt0);
    __syncthreads();   // all layer-1 LDS reads done before H overwrites x

    // ---- norm-act: acc[i*NR16+h][nt][r] holds component i of row (h*16+g4+r) ----
    #pragma unroll
    for (int nt = 0; nt < NPW; ++nt) {
        int w = (wid * NPW + nt) * 16 + wcol;
        #pragma unroll
        for (int h = 0; h < NR16; ++h) {
            #pragma unroll
            for (int r = 0; r < 4; ++r) {
                float s = 0.f;
                #pragma unroll
                for (int i = 0; i < D; ++i) {
                    float v = acc[i * NR16 + h][nt][r];
                    s += v * v;
                }
                float fac = phi_from_sq(s);
                int n = h * 16 + g4 + r;
                #pragma unroll
                for (int i = 0; i < D; ++i) {
                    int R = i * ROWS + n;
                    int idx = (R * U + w) ^ ((R & 7) << 3);
                    lds[idx] = f2bf(acc[i * NR16 + h][nt][r] * fac);
                }
            }
        }
    }
    __syncthreads();

    run_layer(wt1);

    // ---- store fp32 at out[n][OFF + w*D + i]; lanes -> consecutive w ----
    #pragma unroll
    for (int nt = 0; nt < NPW; ++nt) {
        int w = (wid * NPW + nt) * 16 + wcol;
        #pragma unroll
        for (int h = 0; h < NR16; ++h) {
            #pragma unroll
            for (int r = 0; r < 4; ++r) {
                int n = row0 + h * 16 + g4 + r;
                float* po = out + (long)n * 960 + OFF + w * D;
                #pragma unroll
                for (int i = 0; i < D; ++i)
                    po[i] = acc[i * NR16 + h][nt][r];
            }
        }
    }
}

// --- merged kernel: contiguous type ranges ----------------------------------
// bid 0..1023    : l=0, 64-row tiles
// bid 1024..3071 : l=1, 32-row tiles
// bid 3072..5119 : l=2, 32-row tiles
__global__ __launch_bounds__(256, 3) void fused_all(
    const float* __restrict__ x,
    const unsigned short* __restrict__ ws,
    float* __restrict__ out)
{
    __shared__ unsigned short lds[16384];   // 32 KB, max over the 3 types
    int bid = blockIdx.x;
    if (bid < 1024)
        irrep_block<256, 1,   0, 64>(x, ws + 0,     ws + 86016,  out, lds, bid);
    else if (bid < 3072)
        irrep_block<128, 3, 256, 32>(x, ws + 65536, ws + 151552, out, lds, bid - 1024);
    else
        irrep_block< 64, 5, 640, 32>(x, ws + 81920, ws + 167936, out, lds, bid - 3072);
}

extern "C" void kernel_launch(void* const* d_in, const int* in_sizes, int n_in,
                              void* d_out, int out_size, void* d_ws, size_t ws_size,
                              hipStream_t stream)
{
    const float* x  = (const float*)d_in[0];
    const float* W0 = (const float*)d_in[1];  // 256x256
    const float* W1 = (const float*)d_in[2];  // 128x128
    const float* W2 = (const float*)d_in[3];  // 64x64
    const float* W3 = (const float*)d_in[4];  // 256x256
    const float* W4 = (const float*)d_in[5];  // 128x128
    const float* W5 = (const float*)d_in[6];  // 64x64
    unsigned short* ws = (unsigned short*)d_ws;   // 344064 B of bf16 WT
    float* out = (float*)d_out;

    wt_prep<<<672, 256, 0, stream>>>(W0, W1, W2, W3, W4, W5, ws);
    fused_all<<<5120, 256, 0, stream>>>(x, ws, out);
}